// Round 2
// 408.491 us; speedup vs baseline: 1.1065x; 1.1065x over previous
//
#include <hip/hip_runtime.h>
#include <hip/hip_bf16.h>
#include <stdint.h>

#define L_SEQ 131072
#define H_DIM 256
#define P_DIM 64
#define C2    128      // 2*P (re|im)
#define T_CH  128      // chunk length
#define NC    1024     // chunks
#define SUBT  32       // sub-chunk length (per wave)
#define BPAD  136      // padded row of x/Bu LDS buffer (bf16 elements)

typedef unsigned short u16t;
typedef __attribute__((ext_vector_type(8))) short short8;
typedef __attribute__((ext_vector_type(4))) float f32x4;

// ---- workspace map (byte offsets) ----
// W1bf  u16 [128 c][256 h]    @ 0        (65536 B)
// W2bf  u16 [256 h][128 c]    @ 65536    (65536 B)
// LPRE  f32 [128][64]         @ 131072   lambda^(k+1) re
// LPIM  f32 [128][64]         @ 163840
// LAMB  f32 [256]             @ 196608   lbr|lbi|gr|gi
// FR    int [NC]              @ 197632
// CLAST f32 [NC][128]         @ 201728   (524288 B)
// XIN   f32 [NC][128]         @ 726016   (524288 B)
// SL    f32 [NC][4][128]      @ 1250304  (2097152 B)  sub-chunk last states
// SFR   int [NC][4]           @ 3347456  (16384 B)    sub-chunk first-reset
// XLOC  u16 [L][128]          @ 3363840  (33554432 B) scanned (uncorrected) x, bf16
#define OFF_W2_U   32768u
#define OFF_LPRE_F 32768u
#define OFF_LPIM_F 40960u
#define OFF_LAMB_F 49152u
#define OFF_FR_I   49408u
#define OFF_CL_F   50432u
#define OFF_XIN_F  181504u
#define OFF_SL_F   312576u
#define OFF_SFR_I  836864u
#define OFF_XL_U   1681920u

__device__ __forceinline__ float bf2f(unsigned v){
    return __builtin_bit_cast(float, v << 16);
}
// round-to-nearest-even f32 -> bf16 (inputs are finite; no NaN handling needed)
__device__ __forceinline__ u16t f2bf16(float f){
    uint32_t u = __builtin_bit_cast(uint32_t, f);
    u += 0x7fffu + ((u >> 16) & 1u);
    return (u16t)(u >> 16);
}
__device__ __forceinline__ unsigned pk2(float a, float b){
    return (unsigned)f2bf16(a) | ((unsigned)f2bf16(b) << 16);
}

// ---------------- k0: lambda tables + bf16 weight build (merged k0a+k0b) ----------------
// Blocks 0..127: W1 row c=b (each recomputes its single lambda locally — no cross-block dep).
// Blocks 128..255: W2. Block 0 lanes 0..63 additionally build lamb + power tables.
__global__ void k0(const float* __restrict__ Lre, const float* __restrict__ Lim,
                   const float* __restrict__ deltas,
                   const float* __restrict__ Bre, const float* __restrict__ Bim,
                   const float* __restrict__ Cre, const float* __restrict__ Cim,
                   float* __restrict__ wsf, u16t* __restrict__ wsu){
    const int b = blockIdx.x, tid = threadIdx.x;
    if (b == 0 && tid < P_DIM){
        const int p = tid;
        float lr = Lre[p], li = Lim[p], dl = deltas[p];
        float er = expf(lr * dl);
        float si, co; sincosf(li * dl, &si, &co);
        float lbr = er * co, lbi = er * si;
        float den = lr*lr + li*li;
        float gr = ((lbr - 1.f)*lr + lbi*li) / den;
        float gi = (lbi*lr - (lbr - 1.f)*li) / den;
        float* lamb = wsf + OFF_LAMB_F;
        lamb[p] = lbr; lamb[64+p] = lbi; lamb[128+p] = gr; lamb[192+p] = gi;
        float* lpre = wsf + OFF_LPRE_F;
        float* lpim = wsf + OFF_LPIM_F;
        float pr = lbr, pi = lbi;
        for (int k = 0; k < T_CH; k++){
            lpre[k*64 + p] = pr;
            lpim[k*64 + p] = pi;
            float nr = pr*lbr - pi*lbi;
            float ni = pr*lbi + pi*lbr;
            pr = nr; pi = ni;
        }
    }
    if (b < 128){
        const int c = b, h = tid, p = c & 63;
        float lr = Lre[p], li = Lim[p], dl = deltas[p];
        float er = expf(lr * dl);
        float si, co; sincosf(li * dl, &si, &co);
        float lbr = er * co, lbi = er * si;
        float den = lr*lr + li*li;
        float gr = ((lbr - 1.f)*lr + lbi*li) / den;
        float gi = (lbi*lr - (lbr - 1.f)*li) / den;
        float br = Bre[p*H_DIM + h], bi = Bim[p*H_DIM + h];
        float v = (c < 64) ? (gr*br - gi*bi) : (gr*bi + gi*br);
        wsu[c*H_DIM + h] = f2bf16(v);
    } else {
        int i2 = (b - 128)*256 + tid;
        int h = i2 >> 7, c = i2 & 127;
        float v = (c < 64) ? 2.f * Cre[h*P_DIM + c] : -2.f * Cim[h*P_DIM + (c-64)];
        wsu[OFF_W2_U + i2] = f2bf16(v);
    }
}

// ---------------- k1: GEMM1 (f32 in-reg pack) + sub-chunk scan, persist x_local ----------------
__global__ __launch_bounds__(256, 3) void k1(const float* __restrict__ u,
                                             const int* __restrict__ dflag,
                                             float* __restrict__ wsf,
                                             u16t* __restrict__ wsu){
    __shared__ __align__(16) u16t buf[T_CH * BPAD];
    __shared__ int   d_lds[T_CH];
    __shared__ __align__(16) float sublast[4*128];
    __shared__ int   sfr[4];

    const int tid  = threadIdx.x;
    const int w    = tid >> 6, lane = tid & 63;
    const int m    = lane & 15, q = lane >> 4;
    const int cc   = blockIdx.x;
    const int t0   = cc * T_CH;
    const int tg   = t0 + w * SUBT;

    if (tid < T_CH) d_lds[tid] = dflag[t0 + tid];

    // ---- A-fragment preload: f32 -> bf16 pack in registers ----
    uint4 ap[16];
    #pragma unroll
    for (int kf = 0; kf < 8; kf++){
        #pragma unroll
        for (int mt = 0; mt < 2; mt++){
            const float* apn = u + (size_t)(tg + mt*16 + m)*H_DIM + kf*32 + q*8;
            float4 f0 = *(const float4*)apn;
            float4 f1 = *(const float4*)(apn + 4);
            uint4 pk;
            pk.x = pk2(f0.x, f0.y); pk.y = pk2(f0.z, f0.w);
            pk.z = pk2(f1.x, f1.y); pk.w = pk2(f1.z, f1.w);
            ap[kf*2+mt] = pk;
        }
    }

    const u16t* W1 = wsu;
    f32x4 acc[2][8];
    #pragma unroll
    for (int a = 0; a < 2; a++)
        #pragma unroll
        for (int bb = 0; bb < 8; bb++) acc[a][bb] = (f32x4){0.f,0.f,0.f,0.f};

    #pragma unroll
    for (int kf = 0; kf < 8; kf++){
        const int k0v = kf*32 + q*8;
        short8 a0 = __builtin_bit_cast(short8, ap[kf*2+0]);
        short8 a1 = __builtin_bit_cast(short8, ap[kf*2+1]);
        #pragma unroll
        for (int nt = 0; nt < 8; nt++){
            short8 bfr = __builtin_bit_cast(short8, *(const uint4*)(W1 + (nt*16 + m)*H_DIM + k0v));
            acc[0][nt] = __builtin_amdgcn_mfma_f32_16x16x32_bf16(a0, bfr, acc[0][nt], 0,0,0);
            acc[1][nt] = __builtin_amdgcn_mfma_f32_16x16x32_bf16(a1, bfr, acc[1][nt], 0,0,0);
        }
    }
    // Bu -> LDS (bf16)   D layout: col=lane&15, row=quad*4+reg
    #pragma unroll
    for (int mt = 0; mt < 2; mt++)
        #pragma unroll
        for (int nt = 0; nt < 8; nt++){
            int c  = nt*16 + m;
            int tl = w*SUBT + mt*16 + q*4;
            #pragma unroll
            for (int r = 0; r < 4; r++)
                buf[(tl + r)*BPAD + c] = f2bf16(acc[mt][nt][r]);
        }
    __syncthreads();

    // ---- sub-chunk scan WITH writeback (buf becomes scanned x, bf16) ----
    {
        const float* lamb = wsf + OFF_LAMB_F;
        float lbr = lamb[lane], lbi = lamb[64 + lane];
        float xr = 0.f, xi = 0.f;
        int frs = SUBT;
        const int base = w * SUBT;
        for (int tt = 0; tt < SUBT; tt++){
            int tl = base + tt;
            float br = bf2f(buf[tl*BPAD + lane]);
            float bi = bf2f(buf[tl*BPAD + 64 + lane]);
            if (d_lds[tl]){
                if (frs == SUBT) frs = tt;
                xr = br; xi = bi;
            } else {
                float nr = fmaf(lbr, xr, fmaf(-lbi, xi, br));
                float ni = fmaf(lbr, xi, fmaf( lbi, xr, bi));
                xr = nr; xi = ni;
            }
            buf[tl*BPAD + lane]      = f2bf16(xr);
            buf[tl*BPAD + 64 + lane] = f2bf16(xi);
        }
        sublast[w*128 + lane]      = xr;
        sublast[w*128 + 64 + lane] = xi;
        if (lane == 0) sfr[w] = frs;
    }
    __syncthreads();

    // ---- dump scanned x -> XLOC (coalesced uint4) ----
    {
        u16t* xl = wsu + OFF_XL_U + (size_t)t0 * C2;
        #pragma unroll
        for (int i = 0; i < 8; i++){
            int idx = i*256 + tid;
            int row = idx >> 4, c16 = idx & 15;
            *(uint4*)(xl + row*C2 + c16*8) = *(const uint4*)&buf[row*BPAD + c16*8];
        }
    }
    // ---- persist sublast / sfr for k3 ----
    if (tid < 128)
        *(float4*)(wsf + OFF_SL_F + (size_t)cc*512 + tid*4) = *(const float4*)&sublast[tid*4];
    if (tid < 4)
        ((int*)wsf)[OFF_SFR_I + cc*4 + tid] = sfr[tid];

    // ---- chunk aggregate -> clast, fr ----
    if (tid < 64){
        const float* lpre = wsf + OFF_LPRE_F;
        const float* lpim = wsf + OFF_LPIM_F;
        float l32r = lpre[(SUBT-1)*64 + tid], l32i = lpim[(SUBT-1)*64 + tid];
        float xr = 0.f, xi = 0.f;
        int fr_c = T_CH;
        #pragma unroll
        for (int w2 = 0; w2 < 4; w2++){
            float sr = sublast[w2*128 + tid], si = sublast[w2*128 + 64 + tid];
            int f = sfr[w2];
            if (f < SUBT){
                xr = sr; xi = si;
                if (fr_c == T_CH) fr_c = w2*SUBT + f;
            } else {
                float nr = fmaf(l32r, xr, fmaf(-l32i, xi, sr));
                float ni = fmaf(l32r, xi, fmaf( l32i, xr, si));
                xr = nr; xi = ni;
            }
        }
        float* clast = wsf + OFF_CL_F;
        clast[cc*128 + tid]      = xr;
        clast[cc*128 + 64 + tid] = xi;
        if (tid == 0) ((int*)wsf)[OFF_FR_I + cc] = fr_c;
    }
}

// ---------------- k2: serial scan over chunk aggregates ----------------
__global__ void k2(const float* __restrict__ x0re, const float* __restrict__ x0im,
                   float* __restrict__ wsf){
    const int p = threadIdx.x;            // 64 threads
    const float* clast = wsf + OFF_CL_F;
    const int*   frg   = (const int*)wsf + OFF_FR_I;
    float*       xin   = wsf + OFF_XIN_F;
    const float ltr = (wsf + OFF_LPRE_F)[127*64 + p];  // lambda^128
    const float lti = (wsf + OFF_LPIM_F)[127*64 + p];
    float xr = x0re[p], xi = x0im[p];
    const int G = 16;
    float br[G], bi[G], br2[G], bi2[G]; int fr[G], fr2[G];

    auto ldg = [&](int cb, float* A, float* B, int* F){
        #pragma unroll
        for (int j = 0; j < G; j++){
            A[j] = clast[(cb+j)*128 + p];
            B[j] = clast[(cb+j)*128 + 64 + p];
            F[j] = frg[cb+j];
        }
    };
    ldg(0, br, bi, fr);
    for (int g = 0; g < NC / G; g++){
        int cb = g * G;
        if (g + 1 < NC / G) ldg(cb + G, br2, bi2, fr2);
        #pragma unroll
        for (int j = 0; j < G; j++){
            xin[(cb+j)*128 + p]      = xr;
            xin[(cb+j)*128 + 64 + p] = xi;
            if (fr[j] < T_CH){ xr = br[j]; xi = bi[j]; }
            else {
                float nr = fmaf(ltr, xr, fmaf(-lti, xi, br[j]));
                float ni = fmaf(ltr, xi, fmaf( lti, xr, bi[j]));
                xr = nr; xi = ni;
            }
        }
        #pragma unroll
        for (int j = 0; j < G; j++){ br[j]=br2[j]; bi[j]=bi2[j]; fr[j]=fr2[j]; }
    }
}

// ---------------- k3: stage x_local, correct, GEMM2, vectorized epilogue -> y ----------------
__global__ __launch_bounds__(256, 2) void k3(const float* __restrict__ u,
                                             const float* __restrict__ D,
                                             float* __restrict__ wsf,
                                             u16t* __restrict__ wsu,
                                             float* __restrict__ y){
    __shared__ __align__(16) u16t buf[T_CH * BPAD];
    __shared__ float xin_s[4*128];
    __shared__ int   sfr_s[4];

    const int tid  = threadIdx.x;
    const int w    = tid >> 6, lane = tid & 63;
    const int m    = lane & 15, q = lane >> 4;
    const int cc   = blockIdx.x;
    const int t0   = cc * T_CH;
    const int tg   = t0 + w * SUBT;

    // ---- stage XLOC -> buf (reg-staged to allow BPAD padding) ----
    {
        const u16t* xl = wsu + OFF_XL_U + (size_t)t0 * C2;
        uint4 st[8];
        #pragma unroll
        for (int i = 0; i < 8; i++){
            int idx = i*256 + tid;
            st[i] = *(const uint4*)(xl + (idx >> 4)*C2 + (idx & 15)*8);
        }
        #pragma unroll
        for (int i = 0; i < 8; i++){
            int idx = i*256 + tid;
            *(uint4*)&buf[(idx >> 4)*BPAD + (idx & 15)*8] = st[i];
        }
    }
    if (tid < 4) sfr_s[tid] = ((const int*)wsf)[OFF_SFR_I + cc*4 + tid];

    // ---- Phase C: incoming state per sub-chunk (from k1's persisted sublast/sfr + k2's xin) ----
    if (tid < 64){
        const float* lpre = wsf + OFF_LPRE_F;
        const float* lpim = wsf + OFF_LPIM_F;
        const float* xin  = wsf + OFF_XIN_F;
        const float* gsl  = wsf + OFF_SL_F + (size_t)cc*512;
        const int*   gsfr = (const int*)wsf + OFF_SFR_I + cc*4;
        float l32r = lpre[(SUBT-1)*64 + tid], l32i = lpim[(SUBT-1)*64 + tid];
        float xr = xin[cc*128 + tid], xi = xin[cc*128 + 64 + tid];
        #pragma unroll
        for (int w2 = 0; w2 < 4; w2++){
            xin_s[w2*128 + tid]      = xr;
            xin_s[w2*128 + 64 + tid] = xi;
            float sr = gsl[w2*128 + tid], si = gsl[w2*128 + 64 + tid];
            if (gsfr[w2] < SUBT){ xr = sr; xi = si; }
            else {
                float nr = fmaf(l32r, xr, fmaf(-l32i, xi, sr));
                float ni = fmaf(l32r, xi, fmaf( l32i, xr, si));
                xr = nr; xi = ni;
            }
        }
    }
    __syncthreads();

    // ---- Phase D: correction x += lambda^(tt+1) * x_in_sub (rows before sub first-reset) ----
    {
        const float* lpre = wsf + OFF_LPRE_F;
        const float* lpim = wsf + OFF_LPIM_F;
        #pragma unroll 4
        for (int i = 0; i < 32; i++){
            int idx = i*256 + tid;           // pair index over 128 x 64 pairs
            int tl = idx >> 6, j = idx & 63;
            int c0 = j*2;
            int w2 = tl >> 5, tt = tl & 31;
            if (tt < sfr_s[w2]){
                unsigned pr = *(unsigned*)&buf[tl*BPAD + c0];
                float v0 = bf2f(pr & 0xffffu), v1 = bf2f(pr >> 16);
                int p0 = c0 & 63;
                float lr0 = lpre[tt*64 + p0], lr1 = lpre[tt*64 + p0 + 1];
                float li0 = lpim[tt*64 + p0], li1 = lpim[tt*64 + p0 + 1];
                float xr0 = xin_s[w2*128 + p0],      xr1 = xin_s[w2*128 + p0 + 1];
                float xi0 = xin_s[w2*128 + 64 + p0], xi1 = xin_s[w2*128 + 64 + p0 + 1];
                if (c0 < 64){
                    v0 += lr0*xr0 - li0*xi0;
                    v1 += lr1*xr1 - li1*xi1;
                } else {
                    v0 += lr0*xi0 + li0*xr0;
                    v1 += lr1*xi1 + li1*xr1;
                }
                *(unsigned*)&buf[tl*BPAD + c0] = pk2(v0, v1);
            }
        }
    }
    __syncthreads();

    // ---- GEMM2:  y[t][h] = X[t][c] * W2[h][c] ----
    f32x4 acc2[2][16];
    #pragma unroll
    for (int a = 0; a < 2; a++)
        #pragma unroll
        for (int bb = 0; bb < 16; bb++) acc2[a][bb] = (f32x4){0.f,0.f,0.f,0.f};
    {
        const u16t* W2 = wsu + OFF_W2_U;
        #pragma unroll
        for (int ng = 0; ng < 4; ng++){
            #pragma unroll
            for (int kf = 0; kf < 4; kf++){
                const int k0v = kf*32 + q*8;
                short8 a0 = *(const short8*)&buf[(w*SUBT +  0 + m)*BPAD + k0v];
                short8 a1 = *(const short8*)&buf[(w*SUBT + 16 + m)*BPAD + k0v];
                #pragma unroll
                for (int nj = 0; nj < 4; nj++){
                    int nt = ng*4 + nj;
                    short8 bfr = __builtin_bit_cast(short8, *(const uint4*)(W2 + (nt*16 + m)*C2 + k0v));
                    acc2[0][nt] = __builtin_amdgcn_mfma_f32_16x16x32_bf16(a0, bfr, acc2[0][nt], 0,0,0);
                    acc2[1][nt] = __builtin_amdgcn_mfma_f32_16x16x32_bf16(a1, bfr, acc2[1][nt], 0,0,0);
                }
            }
        }
    }
    __syncthreads();   // buf is reused as f32 scratch below (also a compiler ordering fence)

    // ---- Epilogue: per-wave LDS transpose -> float4 u loads, float4 y stores ----
    // per-wave scratch: 16 rows x 132 cols f32 (2112 f32 <= 2176 f32 available)
    {
        float* ep = (float*)&buf[w * SUBT * BPAD];
        float4 dv4[4];
        #pragma unroll
        for (int hj = 0; hj < 4; hj++)
            dv4[hj] = *(const float4*)(D + (hj >> 1)*128 + (hj & 1)*64 + m*4);

        #pragma unroll
        for (int mt = 0; mt < 2; mt++){
            #pragma unroll
            for (int half = 0; half < 2; half++){
                // write: rows q*4+r, cols n2*16+m   (2-way bank aliasing only)
                #pragma unroll
                for (int n2 = 0; n2 < 8; n2++){
                    int nt = half*8 + n2;
                    #pragma unroll
                    for (int r = 0; r < 4; r++)
                        ep[(q*4 + r)*132 + n2*16 + m] = acc2[mt][nt][r];
                }
                __syncthreads();
                // read back transposed + fuse u*D, store float4 (256B contiguous per 16 lanes)
                #pragma unroll
                for (int i = 0; i < 4; i++){
                    int row = q + i*4;
                    size_t t = (size_t)(tg + mt*16 + row);
                    #pragma unroll
                    for (int j = 0; j < 2; j++){
                        int col = j*64 + m*4;
                        float4 v  = *(const float4*)&ep[row*132 + col];
                        float4 uu = *(const float4*)(u + t*H_DIM + half*128 + col);
                        float4 dd = dv4[half*2 + j];
                        float4 o;
                        o.x = fmaf(uu.x, dd.x, v.x);
                        o.y = fmaf(uu.y, dd.y, v.y);
                        o.z = fmaf(uu.z, dd.z, v.z);
                        o.w = fmaf(uu.w, dd.w, v.w);
                        *(float4*)(y + t*H_DIM + half*128 + col) = o;
                    }
                }
                __syncthreads();
            }
        }
    }
}

extern "C" void kernel_launch(void* const* d_in, const int* in_sizes, int n_in,
                              void* d_out, int out_size, void* d_ws, size_t ws_size,
                              hipStream_t stream){
    (void)in_sizes; (void)n_in; (void)out_size; (void)ws_size;
    const float* u      = (const float*)d_in[0];
    const float* Lre    = (const float*)d_in[1];
    const float* Lim    = (const float*)d_in[2];
    const float* Bre    = (const float*)d_in[3];
    const float* Bim    = (const float*)d_in[4];
    const float* Cre    = (const float*)d_in[5];
    const float* Cim    = (const float*)d_in[6];
    const float* D      = (const float*)d_in[7];
    const float* deltas = (const float*)d_in[8];
    const float* x0re   = (const float*)d_in[9];
    const float* x0im   = (const float*)d_in[10];
    const int*   dflag  = (const int*)d_in[11];
    float* wsf = (float*)d_ws;
    u16t*  wsu = (u16t*)d_ws;
    float* y   = (float*)d_out;

    k0<<<256, 256, 0, stream>>>(Lre, Lim, deltas, Bre, Bim, Cre, Cim, wsf, wsu);
    k1<<<NC, 256, 0, stream>>>(u, dflag, wsf, wsu);
    k2<<<1, 64, 0, stream>>>(x0re, x0im, wsf);
    k3<<<NC, 256, 0, stream>>>(u, D, wsf, wsu, y);
}